// Round 1
// baseline (457.298 us; speedup 1.0000x reference)
//
#include <hip/hip_runtime.h>
#include <climits>

// Problem constants (fixed by reference setup_inputs)
constexpr int N_NODES = 50000;
constexpr int N_EDGES = 800000;
constexpr int DIM     = 128;
constexpr float BN_EPS = 1e-5f;

// ---------------------------------------------------------------------------
// Selection of the first-4 (smallest edge index) incoming edges per dst node.
// slots laid out as 4 arrays of N_NODES ints; INT_MAX = empty.
// ---------------------------------------------------------------------------
__global__ void init_slots_kernel(int* __restrict__ slots) {
    int i = blockIdx.x * blockDim.x + threadIdx.x;
    if (i < 4 * N_NODES) slots[i] = INT_MAX;
}

__global__ void select_pass_kernel(const int* __restrict__ dst,
                                   int* __restrict__ slots, int k) {
    int e = blockIdx.x * blockDim.x + threadIdx.x;
    if (e >= N_EDGES) return;
    int v = dst[e];
    // skip edges already selected in earlier slots
    for (int j = 0; j < k; ++j)
        if (slots[j * N_NODES + v] == e) return;
    atomicMin(&slots[k * N_NODES + v], e);
}

// blank_p = W @ blank + b   (128x128 matvec, one block of 128 threads)
__global__ void blank_proj_kernel(const float* __restrict__ W,
                                  const float* __restrict__ b,
                                  const float* __restrict__ blank,
                                  float* __restrict__ bp) {
    int d = threadIdx.x;
    float s = 0.f;
    #pragma unroll 8
    for (int j = 0; j < DIM; ++j) s += W[d * DIM + j] * blank[j];
    bp[d] = s + b[d];
}

__global__ void zero_stats_kernel(float* __restrict__ stats) {
    int i = threadIdx.x;
    if (i < 2 * DIM) stats[i] = 0.f;
}

// Per-node sort-conv: h[v][d] = a*x[v][d] + sum_m cw[m]*sort(msgs)[m] + cb
__global__ void conv_kernel(const float* __restrict__ x,
                            const int* __restrict__ src,
                            const int* __restrict__ slots,
                            const float* __restrict__ bp,
                            const float* __restrict__ cw,
                            const float* __restrict__ cb,
                            const float* __restrict__ a,
                            float* __restrict__ h) {
    const int v = blockIdx.x;
    const int d = threadIdx.x;

    float m0, m1, m2, m3;
    {
        int e0 = slots[0 * N_NODES + v];
        int e1 = slots[1 * N_NODES + v];
        int e2 = slots[2 * N_NODES + v];
        int e3 = slots[3 * N_NODES + v];
        float bpv = bp[d];
        m0 = (e0 != INT_MAX) ? x[src[e0] * DIM + d] : bpv;
        m1 = (e1 != INT_MAX) ? x[src[e1] * DIM + d] : bpv;
        m2 = (e2 != INT_MAX) ? x[src[e2] * DIM + d] : bpv;
        m3 = (e3 != INT_MAX) ? x[src[e3] * DIM + d] : bpv;
    }

    // 4-element ascending sorting network: (0,1)(2,3)(0,2)(1,3)(1,2)
    #define CSWAP(p, q) { float lo = fminf(p, q); float hi = fmaxf(p, q); p = lo; q = hi; }
    CSWAP(m0, m1); CSWAP(m2, m3); CSWAP(m0, m2); CSWAP(m1, m3); CSWAP(m1, m2);
    #undef CSWAP

    float out = cw[0] * m0 + cw[1] * m1 + cw[2] * m2 + cw[3] * m3 + cb[0];
    h[v * DIM + d] = a[0] * x[v * DIM + d] + out;
}

// Column (per-feature) sum and sum-of-squares over all nodes.
__global__ void stats_reduce_kernel(const float* __restrict__ h,
                                    float* __restrict__ stats) {
    const int d = threadIdx.x;           // 128 threads: one per feature
    float s = 0.f, s2 = 0.f;
    for (int v = blockIdx.x; v < N_NODES; v += gridDim.x) {
        float val = h[v * DIM + d];
        s  += val;
        s2 += val * val;
    }
    atomicAdd(&stats[d], s);
    atomicAdd(&stats[DIM + d], s2);
}

__global__ void finalize_stats_kernel(float* __restrict__ stats) {
    int d = threadIdx.x;                 // 128 threads
    float mu  = stats[d] / (float)N_NODES;
    float var = stats[DIM + d] / (float)N_NODES - mu * mu;
    stats[d]       = mu;
    stats[DIM + d] = rsqrtf(var + BN_EPS);
}

// xout = xin + (h - mu) * invstd * g + be    (float4 vectorized)
__global__ void bn_apply_kernel(const float* __restrict__ xin,
                                const float* __restrict__ h,
                                const float* __restrict__ stats,
                                const float* __restrict__ g,
                                const float* __restrict__ be,
                                float* __restrict__ xout) {
    int idx = blockIdx.x * blockDim.x + threadIdx.x;   // float4 index
    constexpr int TOTAL4 = N_NODES * DIM / 4;
    if (idx >= TOTAL4) return;
    int d4 = idx & (DIM / 4 - 1);                      // float4-column within row

    float4 hv = ((const float4*)h)[idx];
    float4 xv = ((const float4*)xin)[idx];
    float4 mu = ((const float4*)stats)[d4];
    float4 iv = ((const float4*)(stats + DIM))[d4];
    float4 gv = ((const float4*)g)[d4];
    float4 bv = ((const float4*)be)[d4];

    float4 o;
    o.x = xv.x + (hv.x - mu.x) * iv.x * gv.x + bv.x;
    o.y = xv.y + (hv.y - mu.y) * iv.y * gv.y + bv.y;
    o.z = xv.z + (hv.z - mu.z) * iv.z * gv.z + bv.z;
    o.w = xv.w + (hv.w - mu.w) * iv.w * gv.w + bv.w;
    ((float4*)xout)[idx] = o;
}

extern "C" void kernel_launch(void* const* d_in, const int* in_sizes, int n_in,
                              void* d_out, int out_size, void* d_ws, size_t ws_size,
                              hipStream_t stream) {
    const float* x0  = (const float*)d_in[0];
    const int*   ei  = (const int*)d_in[1];
    const int*   src = ei;               // edge_index[0]
    const int*   dst = ei + N_EDGES;     // edge_index[1]

    // Per-layer params: W,b,cw,cb,a,g,be,blank at offsets 2 + 8*i
    const float* W[2]; const float* b[2]; const float* cw[2]; const float* cb[2];
    const float* a[2]; const float* g[2]; const float* be[2]; const float* blank[2];
    for (int i = 0; i < 2; ++i) {
        int o = 2 + 8 * i;
        W[i]     = (const float*)d_in[o + 0];
        b[i]     = (const float*)d_in[o + 1];
        cw[i]    = (const float*)d_in[o + 2];
        cb[i]    = (const float*)d_in[o + 3];
        a[i]     = (const float*)d_in[o + 4];
        g[i]     = (const float*)d_in[o + 5];
        be[i]    = (const float*)d_in[o + 6];
        blank[i] = (const float*)d_in[o + 7];
    }

    // Workspace layout (poisoned 0xAA before each call -> init everything used)
    char* ws = (char*)d_ws;
    int*   slots = (int*)ws;                                   // 4*N ints = 800000 B
    float* h     = (float*)(ws + 4 * N_NODES * sizeof(int));   // N*DIM floats = 25.6 MB
    float* stats = (float*)(ws + 4 * N_NODES * sizeof(int)
                               + (size_t)N_NODES * DIM * sizeof(float)); // 256 floats
    float* bp    = stats + 2 * DIM;                            // 128 floats

    float* xout = (float*)d_out;

    // ---- Edge selection (shared by both layers) ----
    init_slots_kernel<<<(4 * N_NODES + 255) / 256, 256, 0, stream>>>(slots);
    for (int k = 0; k < 4; ++k)
        select_pass_kernel<<<(N_EDGES + 255) / 256, 256, 0, stream>>>(dst, slots, k);

    // ---- Two layers ----
    for (int l = 0; l < 2; ++l) {
        const float* xin = (l == 0) ? x0 : xout;
        blank_proj_kernel<<<1, DIM, 0, stream>>>(W[l], b[l], blank[l], bp);
        zero_stats_kernel<<<1, 256, 0, stream>>>(stats);
        conv_kernel<<<N_NODES, DIM, 0, stream>>>(xin, src, slots, bp,
                                                 cw[l], cb[l], a[l], h);
        stats_reduce_kernel<<<256, DIM, 0, stream>>>(h, stats);
        finalize_stats_kernel<<<1, DIM, 0, stream>>>(stats);
        bn_apply_kernel<<<(N_NODES * DIM / 4 + 255) / 256, 256, 0, stream>>>(
            xin, h, stats, g[l], be[l], xout);
    }
}